// Round 5
// baseline (469.586 us; speedup 1.0000x reference)
//
#include <hip/hip_runtime.h>
#include <hip/hip_cooperative_groups.h>

namespace cg = cooperative_groups;

#define NN 20000
#define NE 160000
#define NG 16
#define KP 1024            // padded feature dim
#define MT2 160            // M strips of 128 (padded so tm%8 mapping is uniform)
#define MPAD2 (MT2*128)    // 20480
#define CB 256             // cooperative blocks

typedef __attribute__((ext_vector_type(8))) short bf16x8;
typedef __attribute__((ext_vector_type(4))) float f32x4;

#define GAS __attribute__((address_space(1)))
#define LAS __attribute__((address_space(3)))

__device__ __forceinline__ unsigned short f2bf(float f) {
    unsigned int u = __float_as_uint(f);
    u += 0x7FFFu + ((u >> 16) & 1u);   // round-to-nearest-even
    return (unsigned short)(u >> 16);
}

__device__ __forceinline__ float bf2f(unsigned short u) {
    return __uint_as_float(((unsigned)u) << 16);
}

__device__ __forceinline__ void gld_lds16(const char* g, char* l) {
    __builtin_amdgcn_global_load_lds((GAS void*)g, (LAS void*)l, 16, 0, 0);
}

// ---------------- fused setup (cooperative): init -> deg_cnt -> scan -> scatter
// -> ax -> layer1+W2t. Replaces 6 launches; W1 loaded to LDS once per block. ----
__global__ __launch_bounds__(256) void setup_kernel(
        const float* __restrict__ x, const float* __restrict__ ew,
        const float* __restrict__ W1, const float* __restrict__ b1,
        const float* __restrict__ W2, const float* __restrict__ b2,
        const float* __restrict__ Wf, const int* __restrict__ ei,
        const void* __restrict__ mask,
        float* deg, float* dinv, int* cnt, int* offs, int* cursor, int* flags,
        float* b2p, float* wfp, float* logits, int* ssrc, float* snorm,
        float* Ax, int* bsum, unsigned short* h1, unsigned short* W2t) {
    cg::grid_group grid = cg::this_grid();
    const int t = threadIdx.x;
    const int b = blockIdx.x;
    const int gtid = b * 256 + t;            // 0..65535
    __shared__ int sc[256];
    __shared__ int sb[256];
    __shared__ float w1s[5000];
    __shared__ float axs[80];
    __shared__ float tile[32][33];

    // ---- phase 0: init + mask-format detect ----
    for (int i = gtid; i < NN; i += CB * 256) {
        deg[i] = 2.0f; cnt[i] = 0; cursor[i] = 0; logits[i] = 0.0f;
    }
    if (gtid < KP) {
        b2p[gtid] = (gtid < 1000) ? b2[gtid] : 0.0f;
        wfp[gtid] = (gtid < 1000) ? Wf[gtid] : 0.0f;
    }
    if (gtid < 2) flags[gtid] = 0;
    if (gtid < 5000) {
        const unsigned v = ((const unsigned*)mask)[gtid];
        if (v > 1u) atomicOr(&flags[0], 1);                      // not int32 {0,1}
        if (v != 0u && v != 0x3F800000u) atomicOr(&flags[1], 1); // not float32 {0,1.0f}
    }
    grid.sync();

    // ---- phase 1: degree + count ----
    for (int e = gtid; e < NE; e += CB * 256) {
        const int c = ei[NE + e];
        atomicAdd(&deg[c], ew[e]);
        atomicAdd(&cnt[c], 1);
    }
    grid.sync();

    // ---- phase 2: exclusive scan of cnt (two-level) + dinv ----
    int myc = 0;
    if (gtid < NN) {
        myc = cnt[gtid];
        const float d = deg[gtid];
        dinv[gtid] = (d > 0.0f) ? (1.0f / sqrtf(d)) : 0.0f;
    }
    sc[t] = myc;
    __syncthreads();
    for (int off = 1; off < 256; off <<= 1) {
        const int u = (t >= off) ? sc[t - off] : 0;
        __syncthreads();
        sc[t] += u;
        __syncthreads();
    }
    if (t == 255) bsum[b] = sc[255];
    grid.sync();
    if (b == 0) {
        const int v = bsum[t];
        sb[t] = v;
        __syncthreads();
        for (int off = 1; off < 256; off <<= 1) {
            const int u = (t >= off) ? sb[t - off] : 0;
            __syncthreads();
            sb[t] += u;
            __syncthreads();
        }
        bsum[t] = sb[t] - v;   // exclusive block prefix
    }
    grid.sync();
    if (gtid < NN) offs[gtid] = (sc[t] - myc) + bsum[b];
    grid.sync();

    // ---- phase 3: counting-sort scatter of edges by destination ----
    for (int e = gtid; e < NE; e += CB * 256) {
        const int r = ei[e], c = ei[NE + e];
        const int pos = atomicAdd(&cursor[c], 1);
        const int idx = offs[c] + pos;
        ssrc[idx] = r;
        snorm[idx] = dinv[r] * ew[e] * dinv[c];
    }
    grid.sync();

    // ---- phase 4: Ax = A_norm * x (5-wide gather, self-loop folded) ----
    for (int i = gtid; i < NN; i += CB * 256) {
        float a0 = 0, a1 = 0, a2 = 0, a3 = 0, a4 = 0;
        const int s0 = offs[i], n = cnt[i];
        for (int e = s0; e < s0 + n; ++e) {
            const int r = ssrc[e];
            const float w = snorm[e];
            const float* xr = x + r * 5;
            a0 += w * xr[0]; a1 += w * xr[1]; a2 += w * xr[2];
            a3 += w * xr[3]; a4 += w * xr[4];
        }
        const float wl = 2.0f * dinv[i] * dinv[i];
        const float* xi = x + i * 5;
        a0 += wl * xi[0]; a1 += wl * xi[1]; a2 += wl * xi[2];
        a3 += wl * xi[3]; a4 += wl * xi[4];
        float* o = Ax + i * 5;
        o[0] = a0; o[1] = a1; o[2] = a2; o[3] = a3; o[4] = a4;
    }
    grid.sync();

    // ---- phase 5: layer1 (chunks 0..1249, 16 nodes each) + W2t (1250..2273) ----
    for (int idx = t; idx < 1250; idx += 256)          // W1 -> LDS once per block
        ((float4*)w1s)[idx] = ((const float4*)W1)[idx];
    for (int ch = b; ch < 2274; ch += CB) {
        __syncthreads();
        if (ch < 1250) {
            const int nb = ch * 16;
            if (t < 80) axs[t] = Ax[nb * 5 + t];
            __syncthreads();
            if (t < 250) {
                const int c0 = t * 4;
                float w[5][4];
#pragma unroll
                for (int f = 0; f < 5; ++f) {
                    const float4 wv = ((const float4*)w1s)[f * 250 + t];
                    w[f][0] = wv.x; w[f][1] = wv.y; w[f][2] = wv.z; w[f][3] = wv.w;
                }
                const float4 bb = *(const float4*)(b1 + c0);
                for (int n = 0; n < 16; ++n) {
                    float r0 = bb.x, r1 = bb.y, r2 = bb.z, r3 = bb.w;
#pragma unroll
                    for (int f = 0; f < 5; ++f) {
                        const float av = axs[n * 5 + f];
                        r0 += av * w[f][0]; r1 += av * w[f][1];
                        r2 += av * w[f][2]; r3 += av * w[f][3];
                    }
                    ushort4 pk;
                    pk.x = f2bf(fmaxf(r0, 0.f)); pk.y = f2bf(fmaxf(r1, 0.f));
                    pk.z = f2bf(fmaxf(r2, 0.f)); pk.w = f2bf(fmaxf(r3, 0.f));
                    *(ushort4*)(h1 + (size_t)(nb + n) * KP + c0) = pk;
                }
            } else {
                const int c0 = 1000 + (t - 250) * 4;   // zero pad cols 1000..1023
                ushort4 zz = {0, 0, 0, 0};
                for (int n = 0; n < 16; ++n)
                    *(ushort4*)(h1 + (size_t)(nb + n) * KP + c0) = zz;
            }
        } else {
            const int bw = ch - 1250;
            const int n0 = (bw & 31) * 32;
            const int k0 = (bw >> 5) * 32;
            const int tx = t & 31, ty = t >> 5;        // 32 x 8
#pragma unroll
            for (int j = 0; j < 4; ++j) {
                const int k = k0 + ty + j * 8;
                const int n = n0 + tx;
                tile[ty + j * 8][tx] = (k < 1000 && n < 1000) ? W2[k * 1000 + n] : 0.0f;
            }
            __syncthreads();
#pragma unroll
            for (int j = 0; j < 4; ++j) {
                const int n = n0 + ty + j * 8;
                const int k = k0 + tx;
                W2t[(size_t)n * KP + k] = f2bf(tile[tx][ty + j * 8]);
            }
        }
    }
}

// G = A_norm * h1. Edge meta staged in LDS (64-edge chunks); 2 edge-parities x
// 2-deep unroll = 4 rows in flight. Pad rows [NN, MPAD2) written as zeros.
__global__ __launch_bounds__(256) void agg1k_kernel(const unsigned short* __restrict__ h1,
        const int* __restrict__ ssrc, const float* __restrict__ snorm,
        const int* __restrict__ offs, const int* __restrict__ cnt,
        const float* __restrict__ dinv, unsigned short* __restrict__ G) {
    const int i = blockIdx.x;
    const int t = threadIdx.x;
    const int sub = t >> 7;          // 0/1: edge parity
    const int tc = t & 127;          // col group: cols [tc*8, tc*8+8)
    unsigned short* grow = G + (size_t)i * KP + tc * 8;
    if (i >= NN) {
        if (sub == 0) {
            bf16x8 z = {0,0,0,0,0,0,0,0};
            *(bf16x8*)grow = z;
        }
        return;
    }
    __shared__ int   se[64];
    __shared__ float sw[64];
    float acc[8] = {0,0,0,0,0,0,0,0};
    float acc2[8] = {0,0,0,0,0,0,0,0};
    const int s0 = offs[i], n = cnt[i];
    for (int base = 0; base < n; base += 64) {
        const int m = (n - base < 64) ? (n - base) : 64;
        __syncthreads();
        if (t < m) { se[t] = ssrc[s0 + base + t]; sw[t] = snorm[s0 + base + t]; }
        __syncthreads();
        int e = sub;
        for (; e + 2 < m; e += 4) {       // two independent load+acc chains
            const int r0 = se[e];     const float w0 = sw[e];
            const int r1 = se[e + 2]; const float w1 = sw[e + 2];
            const bf16x8 v0 = *(const bf16x8*)(h1 + (size_t)r0 * KP + tc * 8);
            const bf16x8 v1 = *(const bf16x8*)(h1 + (size_t)r1 * KP + tc * 8);
#pragma unroll
            for (int j = 0; j < 8; ++j) acc[j]  += w0 * bf2f((unsigned short)v0[j]);
#pragma unroll
            for (int j = 0; j < 8; ++j) acc2[j] += w1 * bf2f((unsigned short)v1[j]);
        }
        for (; e < m; e += 2) {
            const int r = se[e];
            const float w = sw[e];
            const bf16x8 hv = *(const bf16x8*)(h1 + (size_t)r * KP + tc * 8);
#pragma unroll
            for (int j = 0; j < 8; ++j) acc[j] += w * bf2f((unsigned short)hv[j]);
        }
    }
    if (sub == 0) {
        const float wl = 2.0f * dinv[i] * dinv[i];
        const bf16x8 hv = *(const bf16x8*)(h1 + (size_t)i * KP + tc * 8);
#pragma unroll
        for (int j = 0; j < 8; ++j) acc[j] += wl * bf2f((unsigned short)hv[j]);
    }
#pragma unroll
    for (int j = 0; j < 8; ++j) acc[j] += acc2[j];
    __shared__ float red[128][8];
    if (sub == 1) {
#pragma unroll
        for (int j = 0; j < 8; ++j) red[tc][j] = acc[j];
    }
    __syncthreads();
    if (sub == 0) {
        bf16x8 o;
#pragma unroll
        for (int j = 0; j < 8; ++j) o[j] = (short)f2bf(acc[j] + red[tc][j]);
        *(bf16x8*)grow = o;
    }
}

// logits += sum_cols relu(G @ W2 + b2) * Wf — fused epilogue, R2-proven 128x128
// tile / BK=32 / width-16 global_load_lds / XOR-swizzled LDS (76 VGPR, 16 KB).
// Block mapping: linear id, tm = (bid>>6)*8 + (bid&7), tn = (bid>>3)&7, so
// id%8 == tm%8 — all 8 tn-readers of an A-strip are temporally adjacent AND on
// one XCD (round-robin id->XCD), keeping the 256 KB strip in that L2; B (2 MB)
// is L2-resident everywhere.
__global__ __launch_bounds__(256) void gemm_kernel(const unsigned short* __restrict__ A,
                                                   const unsigned short* __restrict__ B,
                                                   const float* __restrict__ b2p,
                                                   const float* __restrict__ wfp,
                                                   float* __restrict__ logits) {
    __shared__ unsigned short As[4096];  // 128 rows x 32 k (bf16) = 8 KB
    __shared__ unsigned short Bs[4096];
    const int bid = blockIdx.x;
    const int tm = (bid >> 6) * 8 + (bid & 7);   // 0..159, tm%8 == bid%8
    const int tn = (bid >> 3) & 7;
    const int tid = threadIdx.x;
    const int lane = tid & 63;
    const int wv = tid >> 6;
    const int wr = wv >> 1, wc = wv & 1;

    // staging: lane handles 16B chunk; global chunk is XOR-swizzled by row pair
    const int chunk = ((tid & 3) ^ ((tid >> 3) & 3)) * 16;
    const int rsub = tid >> 2;   // row 0..63 (+64 in round 1)
    const char* Ag = (const char*)(A + (size_t)(tm * 128 + rsub) * KP) + chunk;
    const char* Bg = (const char*)(B + (size_t)(tn * 128 + rsub) * KP) + chunk;
    char* AsW = (char*)As + wv * 1024;
    char* BsW = (char*)Bs + wv * 1024;

    f32x4 acc[4][4];
#pragma unroll
    for (int i = 0; i < 4; ++i)
#pragma unroll
        for (int j = 0; j < 4; ++j) acc[i][j] = (f32x4){0.f, 0.f, 0.f, 0.f};

    const int m = lane & 15;
    const int quad = lane >> 4;
    const int sw = quad ^ ((m >> 1) & 3);       // swizzled k-chunk slot
    const int aoff = (wr * 64 + m) * 64 + sw * 16;  // byte offset, mt stride = 1024B
    const int boff = (wc * 64 + m) * 64 + sw * 16;

    for (int kk = 0; kk < KP; kk += 32) {
        __syncthreads();
        const int kb = kk * 2;
        gld_lds16(Ag + kb,             AsW);
        gld_lds16(Ag + kb + 64 * 2048, AsW + 4096);
        gld_lds16(Bg + kb,             BsW);
        gld_lds16(Bg + kb + 64 * 2048, BsW + 4096);
        __syncthreads();
        bf16x8 af[4], bfv[4];
#pragma unroll
        for (int mt = 0; mt < 4; ++mt)
            af[mt] = *(const bf16x8*)((const char*)As + aoff + mt * 1024);
#pragma unroll
        for (int nt = 0; nt < 4; ++nt)
            bfv[nt] = *(const bf16x8*)((const char*)Bs + boff + nt * 1024);
#pragma unroll
        for (int mt = 0; mt < 4; ++mt)
#pragma unroll
            for (int nt = 0; nt < 4; ++nt)
                acc[mt][nt] = __builtin_amdgcn_mfma_f32_16x16x32_bf16(af[mt], bfv[nt], acc[mt][nt], 0, 0, 0);
    }

    // epilogue: C/D layout col = lane&15, row = quad*4 + reg.
    const int col0 = tn * 128 + wc * 64 + m;
    const int row00 = tm * 128 + wr * 64 + quad * 4;
#pragma unroll
    for (int mt = 0; mt < 4; ++mt) {
        float ps0 = 0.f, ps1 = 0.f, ps2 = 0.f, ps3 = 0.f;
#pragma unroll
        for (int nt = 0; nt < 4; ++nt) {
            const int c = col0 + nt * 16;
            const float bb = b2p[c];
            const float wf = wfp[c];
            ps0 += fmaxf(acc[mt][nt][0] + bb, 0.f) * wf;
            ps1 += fmaxf(acc[mt][nt][1] + bb, 0.f) * wf;
            ps2 += fmaxf(acc[mt][nt][2] + bb, 0.f) * wf;
            ps3 += fmaxf(acc[mt][nt][3] + bb, 0.f) * wf;
        }
#pragma unroll
        for (int msk = 1; msk < 16; msk <<= 1) {
            ps0 += __shfl_xor(ps0, msk);
            ps1 += __shfl_xor(ps1, msk);
            ps2 += __shfl_xor(ps2, msk);
            ps3 += __shfl_xor(ps3, msk);
        }
        if (m == 0) {
            const int row = row00 + mt * 16;
            if (row + 0 < NN) atomicAdd(&logits[row + 0], ps0);
            if (row + 1 < NN) atomicAdd(&logits[row + 1], ps1);
            if (row + 2 < NN) atomicAdd(&logits[row + 2], ps2);
            if (row + 3 < NN) atomicAdd(&logits[row + 3], ps3);
        }
    }
}

// masked segment softmax; batch sorted -> binary-search graph range.
// bf bias dropped (uniform shift cancels in softmax).
__global__ __launch_bounds__(256) void softmax_kernel(const float* __restrict__ logits,
        const void* __restrict__ mask, const int* __restrict__ flags,
        const int* __restrict__ batch, float* __restrict__ out) {
    const int g = blockIdx.x;
    const int t = threadIdx.x;
    __shared__ int s_lo, s_hi;
    __shared__ float red[4];
    __shared__ float sval;
    if (t == 0) {
        int lo = 0, hi = NN;
        while (lo < hi) { const int mid = (lo + hi) >> 1; if (batch[mid] < g) lo = mid + 1; else hi = mid; }
        s_lo = lo;
        int lo2 = lo, hi2 = NN;
        while (lo2 < hi2) { const int mid = (lo2 + hi2) >> 1; if (batch[mid] < g + 1) lo2 = mid + 1; else hi2 = mid; }
        s_hi = lo2;
    }
    __syncthreads();
    const int lo = s_lo, hi = s_hi;
    const int f0 = flags[0], f1 = flags[1];
    auto mget = [&](int i) -> int {
        if (f0 == 0) return ((const int*)mask)[i] != 0;
        if (f1 == 0) return ((const unsigned*)mask)[i] != 0u;
        return ((const unsigned char*)mask)[i] != 0;
    };
    float mx = -1e30f;
    for (int i = lo + t; i < hi; i += 256)
        if (mget(i)) mx = fmaxf(mx, logits[i]);
    for (int off = 32; off; off >>= 1) mx = fmaxf(mx, __shfl_down(mx, off));
    if ((t & 63) == 0) red[t >> 6] = mx;
    __syncthreads();
    if (t == 0) sval = fmaxf(fmaxf(red[0], red[1]), fmaxf(red[2], red[3]));
    __syncthreads();
    mx = sval;
    __syncthreads();
    float sm = 0.f;
    for (int i = lo + t; i < hi; i += 256)
        if (mget(i)) sm += expf(logits[i] - mx);
    for (int off = 32; off; off >>= 1) sm += __shfl_down(sm, off);
    if ((t & 63) == 0) red[t >> 6] = sm;
    __syncthreads();
    if (t == 0) sval = red[0] + red[1] + red[2] + red[3];
    __syncthreads();
    const float inv = 1.0f / fmaxf(sval, 1e-16f);
    for (int i = lo + t; i < hi; i += 256)
        out[i] = mget(i) ? expf(logits[i] - mx) * inv : 0.0f;
}

extern "C" void kernel_launch(void* const* d_in, const int* in_sizes, int n_in,
                              void* d_out, int out_size, void* d_ws, size_t ws_size,
                              hipStream_t stream) {
    (void)in_sizes; (void)n_in; (void)out_size; (void)ws_size;
    const float* x   = (const float*)d_in[0];
    const float* ew  = (const float*)d_in[1];
    const float* W1  = (const float*)d_in[2];
    const float* b1  = (const float*)d_in[3];
    const float* W2  = (const float*)d_in[4];
    const float* b2  = (const float*)d_in[5];
    const float* Wf  = (const float*)d_in[6];
    const int*   ei  = (const int*)d_in[8];
    const void*  mask  = d_in[9];
    const int*   batch = (const int*)d_in[10];
    float* out = (float*)d_out;

    char* p = (char*)d_ws;
    auto carve = [&](size_t bytes) { char* q = p; p += (bytes + 255) & ~(size_t)255; return q; };
    float* deg    = (float*)carve(NN * 4);
    float* dinv   = (float*)carve(NN * 4);
    int*   cnt    = (int*)carve(NN * 4);
    int*   offs   = (int*)carve(NN * 4);
    int*   cursor = (int*)carve(NN * 4);
    int*   flags  = (int*)carve(256);
    int*   bsum   = (int*)carve(CB * 4);
    int*   ssrc   = (int*)carve(NE * 4);
    float* snorm  = (float*)carve(NE * 4);
    float* Ax     = (float*)carve(NN * 5 * 4);
    float* b2p    = (float*)carve(KP * 4);
    float* wfp    = (float*)carve(KP * 4);
    float* logits = (float*)carve(NN * 4);
    unsigned short* W2t = (unsigned short*)carve((size_t)KP * KP * 2);
    unsigned short* h1  = (unsigned short*)carve((size_t)NN * KP * 2);
    unsigned short* G   = (unsigned short*)carve((size_t)MPAD2 * KP * 2);

    void* cargs[] = {
        (void*)&x, (void*)&ew, (void*)&W1, (void*)&b1, (void*)&W2, (void*)&b2,
        (void*)&Wf, (void*)&ei, (void*)&mask,
        (void*)&deg, (void*)&dinv, (void*)&cnt, (void*)&offs, (void*)&cursor,
        (void*)&flags, (void*)&b2p, (void*)&wfp, (void*)&logits, (void*)&ssrc,
        (void*)&snorm, (void*)&Ax, (void*)&bsum, (void*)&h1, (void*)&W2t
    };
    hipLaunchCooperativeKernel((void*)setup_kernel, dim3(CB), dim3(256), cargs, 0, stream);
    hipLaunchKernelGGL(agg1k_kernel,   dim3(MPAD2), dim3(256), 0, stream, h1, ssrc, snorm, offs, cnt, dinv, G);
    hipLaunchKernelGGL(gemm_kernel,    dim3(MT2 * 8), dim3(256), 0, stream, G, W2t, b2p, wfp, logits);
    hipLaunchKernelGGL(softmax_kernel, dim3(NG),    dim3(256), 0, stream, logits, mask, flags, batch, out);
}

// Round 6
// 336.305 us; speedup vs baseline: 1.3963x; 1.3963x over previous
//
#include <hip/hip_runtime.h>

#define NN 20000
#define NE 160000
#define NG 16
#define KP 1024            // padded feature dim
#define MT2 160            // M strips of 128 (padded so tm%8 mapping is uniform)
#define MPAD2 (MT2*128)    // 20480

typedef __attribute__((ext_vector_type(8))) short bf16x8;
typedef __attribute__((ext_vector_type(4))) float f32x4;

#define GAS __attribute__((address_space(1)))
#define LAS __attribute__((address_space(3)))

__device__ __forceinline__ unsigned short f2bf(float f) {
    unsigned int u = __float_as_uint(f);
    u += 0x7FFFu + ((u >> 16) & 1u);   // round-to-nearest-even
    return (unsigned short)(u >> 16);
}

__device__ __forceinline__ float bf2f(unsigned short u) {
    return __uint_as_float(((unsigned)u) << 16);
}

__device__ __forceinline__ void gld_lds16(const char* g, char* l) {
    __builtin_amdgcn_global_load_lds((GAS void*)g, (LAS void*)l, 16, 0, 0);
}

// deg/cnt/cursor/logits/Ax are zeroed by one hipMemsetAsync before this.
__global__ void deg_cnt_kernel(const int* __restrict__ ei, const float* __restrict__ ew,
                               float* deg, int* cnt) {
    const int e = blockIdx.x * blockDim.x + threadIdx.x;
    if (e >= NE) return;
    const int c = ei[NE + e];
    atomicAdd(&deg[c], ew[e]);
    atomicAdd(&cnt[c], 1);
}

// prefix-sum of cnt + dinv. Self-loop weight 2.0 folded: dinv = 1/sqrt(2 + sum_ew).
__global__ __launch_bounds__(1024) void scan_kernel(const int* __restrict__ cnt,
                                                    const float* __restrict__ deg,
                                                    int* __restrict__ offs,
                                                    float* __restrict__ dinv) {
    __shared__ int part[1024];
    const int t = threadIdx.x;
    const int base = t * 20;   // 1024*20 >= 20000
    int s = 0;
    for (int j = 0; j < 20; ++j) {
        const int i = base + j;
        if (i < NN) {
            s += cnt[i];
            dinv[i] = 1.0f / sqrtf(2.0f + deg[i]);   // always > 0
        }
    }
    part[t] = s;
    __syncthreads();
    for (int off = 1; off < 1024; off <<= 1) {
        int u = (t >= off) ? part[t - off] : 0;
        __syncthreads();
        part[t] += u;
        __syncthreads();
    }
    int run = part[t] - s;   // exclusive prefix of this chunk
    for (int j = 0; j < 20; ++j) {
        const int i = base + j;
        if (i < NN) { offs[i] = run; run += cnt[i]; }
    }
}

// counting-sort scatter + Ax accumulation fused (Ax += norm * x[r], 5 atomics/edge;
// self-loop term added later in prep). Ax was zeroed by the memset.
__global__ void scatter_ax_kernel(const int* __restrict__ ei, const float* __restrict__ ew,
                                  const float* __restrict__ dinv, const int* __restrict__ offs,
                                  int* cursor, int* __restrict__ ssrc, float* __restrict__ snorm,
                                  const float* __restrict__ x, float* __restrict__ Ax) {
    const int e = blockIdx.x * blockDim.x + threadIdx.x;
    if (e >= NE) return;
    const int r = ei[e], c = ei[NE + e];
    const float nrm = dinv[r] * ew[e] * dinv[c];
    const int pos = atomicAdd(&cursor[c], 1);
    const int idx = offs[c] + pos;
    ssrc[idx] = r;
    snorm[idx] = nrm;
    const float* xr = x + r * 5;
    float* axc = Ax + c * 5;
#pragma unroll
    for (int j = 0; j < 5; ++j) atomicAdd(&axc[j], nrm * xr[j]);
}

// prep = layer1 (blocks 0..1249, 16 nodes each, W1 staged in LDS; self-loop Ax term
// folded into the LDS read) + W2 transpose (blocks 1250..2273).
__global__ __launch_bounds__(256) void prep_kernel(const float* __restrict__ Ax,
        const float* __restrict__ x, const float* __restrict__ dinv,
        const float* __restrict__ W1, const float* __restrict__ b1,
        unsigned short* __restrict__ h1,
        const float* __restrict__ W2, unsigned short* __restrict__ W2t) {
    const int bid = blockIdx.x;
    const int t = threadIdx.x;
    if (bid < 1250) {
        // ---- layer1: h1 = relu((Ax + selfloop) @ W1 + b1) as bf16 [rows x KP] ----
        __shared__ float w1s[5000];
        __shared__ float axs[80];
        for (int idx = t; idx < 1250; idx += 256)
            ((float4*)w1s)[idx] = ((const float4*)W1)[idx];
        const int nb = bid * 16;
        if (t < 80) {
            const int node = nb + t / 5;
            const float dv = dinv[node];
            axs[t] = Ax[nb * 5 + t] + 2.0f * dv * dv * x[nb * 5 + t];
        }
        __syncthreads();
        if (t < 250) {
            const int c0 = t * 4;
            float w[5][4];
#pragma unroll
            for (int f = 0; f < 5; ++f) {
                const float4 wv = ((const float4*)w1s)[f * 250 + t];
                w[f][0] = wv.x; w[f][1] = wv.y; w[f][2] = wv.z; w[f][3] = wv.w;
            }
            const float4 bb = *(const float4*)(b1 + c0);
            for (int n = 0; n < 16; ++n) {
                float r0 = bb.x, r1 = bb.y, r2 = bb.z, r3 = bb.w;
#pragma unroll
                for (int f = 0; f < 5; ++f) {
                    const float av = axs[n * 5 + f];
                    r0 += av * w[f][0]; r1 += av * w[f][1];
                    r2 += av * w[f][2]; r3 += av * w[f][3];
                }
                ushort4 pk;
                pk.x = f2bf(fmaxf(r0, 0.f)); pk.y = f2bf(fmaxf(r1, 0.f));
                pk.z = f2bf(fmaxf(r2, 0.f)); pk.w = f2bf(fmaxf(r3, 0.f));
                *(ushort4*)(h1 + (size_t)(nb + n) * KP + c0) = pk;
            }
        } else {
            const int c0 = 1000 + (t - 250) * 4;   // zero pad cols 1000..1023
            ushort4 zz = {0, 0, 0, 0};
            for (int n = 0; n < 16; ++n)
                *(ushort4*)(h1 + (size_t)(nb + n) * KP + c0) = zz;
        }
    } else {
        // ---- W2t[n][k] = bf16(W2[k][n]) zero-padded to 1024x1024 ----
        __shared__ float tile[32][33];
        const int bw = bid - 1250;
        const int n0 = (bw & 31) * 32;
        const int k0 = (bw >> 5) * 32;
        const int tx = t & 31, ty = t >> 5;        // 32 x 8
#pragma unroll
        for (int j = 0; j < 4; ++j) {
            const int k = k0 + ty + j * 8;
            const int n = n0 + tx;
            tile[ty + j * 8][tx] = (k < 1000 && n < 1000) ? W2[k * 1000 + n] : 0.0f;
        }
        __syncthreads();
#pragma unroll
        for (int j = 0; j < 4; ++j) {
            const int n = n0 + ty + j * 8;
            const int k = k0 + tx;
            W2t[(size_t)n * KP + k] = f2bf(tile[tx][ty + j * 8]);
        }
    }
}

// G = A_norm * h1. Edge meta staged in LDS (64-edge chunks); 2 edge-parities x
// 2-deep unroll = 4 rows in flight. Pad rows [NN, MPAD2) written as zeros.
__global__ __launch_bounds__(256) void agg1k_kernel(const unsigned short* __restrict__ h1,
        const int* __restrict__ ssrc, const float* __restrict__ snorm,
        const int* __restrict__ offs, const int* __restrict__ cnt,
        const float* __restrict__ dinv, unsigned short* __restrict__ G) {
    const int i = blockIdx.x;
    const int t = threadIdx.x;
    const int sub = t >> 7;          // 0/1: edge parity
    const int tc = t & 127;          // col group: cols [tc*8, tc*8+8)
    unsigned short* grow = G + (size_t)i * KP + tc * 8;
    if (i >= NN) {
        if (sub == 0) {
            bf16x8 z = {0,0,0,0,0,0,0,0};
            *(bf16x8*)grow = z;
        }
        return;
    }
    __shared__ int   se[64];
    __shared__ float sw[64];
    float acc[8] = {0,0,0,0,0,0,0,0};
    float acc2[8] = {0,0,0,0,0,0,0,0};
    const int s0 = offs[i], n = cnt[i];
    for (int base = 0; base < n; base += 64) {
        const int m = (n - base < 64) ? (n - base) : 64;
        __syncthreads();
        if (t < m) { se[t] = ssrc[s0 + base + t]; sw[t] = snorm[s0 + base + t]; }
        __syncthreads();
        int e = sub;
        for (; e + 2 < m; e += 4) {       // two independent load+acc chains
            const int r0 = se[e];     const float w0 = sw[e];
            const int r1 = se[e + 2]; const float w1 = sw[e + 2];
            const bf16x8 v0 = *(const bf16x8*)(h1 + (size_t)r0 * KP + tc * 8);
            const bf16x8 v1 = *(const bf16x8*)(h1 + (size_t)r1 * KP + tc * 8);
#pragma unroll
            for (int j = 0; j < 8; ++j) acc[j]  += w0 * bf2f((unsigned short)v0[j]);
#pragma unroll
            for (int j = 0; j < 8; ++j) acc2[j] += w1 * bf2f((unsigned short)v1[j]);
        }
        for (; e < m; e += 2) {
            const int r = se[e];
            const float w = sw[e];
            const bf16x8 hv = *(const bf16x8*)(h1 + (size_t)r * KP + tc * 8);
#pragma unroll
            for (int j = 0; j < 8; ++j) acc[j] += w * bf2f((unsigned short)hv[j]);
        }
    }
    if (sub == 0) {
        const float wl = 2.0f * dinv[i] * dinv[i];
        const bf16x8 hv = *(const bf16x8*)(h1 + (size_t)i * KP + tc * 8);
#pragma unroll
        for (int j = 0; j < 8; ++j) acc[j] += wl * bf2f((unsigned short)hv[j]);
    }
#pragma unroll
    for (int j = 0; j < 8; ++j) acc[j] += acc2[j];
    __shared__ float red[128][8];
    if (sub == 1) {
#pragma unroll
        for (int j = 0; j < 8; ++j) red[tc][j] = acc[j];
    }
    __syncthreads();
    if (sub == 0) {
        bf16x8 o;
#pragma unroll
        for (int j = 0; j < 8; ++j) o[j] = (short)f2bf(acc[j] + red[tc][j]);
        *(bf16x8*)grow = o;
    }
}

// logits += sum_cols relu(G @ W2 + b2) * Wf — fused epilogue, R2-proven 128x128
// tile / BK=32 / width-16 global_load_lds / XOR-swizzled LDS (76 VGPR, 16 KB).
// Block mapping: tm = (bid>>6)*8 + (bid&7), tn = (bid>>3)&7 — id%8 == tm%8, so
// the 8 tn-readers of one A-strip are temporally adjacent and (if id->XCD is
// round-robin) on one XCD: A-strip fetched into that L2 once. B (2 MB) is
// L2-resident everywhere.
__global__ __launch_bounds__(256) void gemm_kernel(const unsigned short* __restrict__ A,
                                                   const unsigned short* __restrict__ B,
                                                   const float* __restrict__ b2,
                                                   const float* __restrict__ Wf,
                                                   float* __restrict__ logits) {
    __shared__ unsigned short As[4096];  // 128 rows x 32 k (bf16) = 8 KB
    __shared__ unsigned short Bs[4096];
    const int bid = blockIdx.x;
    const int tm = (bid >> 6) * 8 + (bid & 7);   // 0..159, tm%8 == bid%8
    const int tn = (bid >> 3) & 7;
    const int tid = threadIdx.x;
    const int lane = tid & 63;
    const int wv = tid >> 6;
    const int wr = wv >> 1, wc = wv & 1;

    // staging: lane handles 16B chunk; global chunk is XOR-swizzled by row pair
    const int chunk = ((tid & 3) ^ ((tid >> 3) & 3)) * 16;
    const int rsub = tid >> 2;   // row 0..63 (+64 in round 1)
    const char* Ag = (const char*)(A + (size_t)(tm * 128 + rsub) * KP) + chunk;
    const char* Bg = (const char*)(B + (size_t)(tn * 128 + rsub) * KP) + chunk;
    char* AsW = (char*)As + wv * 1024;
    char* BsW = (char*)Bs + wv * 1024;

    f32x4 acc[4][4];
#pragma unroll
    for (int i = 0; i < 4; ++i)
#pragma unroll
        for (int j = 0; j < 4; ++j) acc[i][j] = (f32x4){0.f, 0.f, 0.f, 0.f};

    const int m = lane & 15;
    const int quad = lane >> 4;
    const int sw = quad ^ ((m >> 1) & 3);       // swizzled k-chunk slot
    const int aoff = (wr * 64 + m) * 64 + sw * 16;  // byte offset, mt stride = 1024B
    const int boff = (wc * 64 + m) * 64 + sw * 16;

    for (int kk = 0; kk < KP; kk += 32) {
        __syncthreads();
        const int kb = kk * 2;
        gld_lds16(Ag + kb,             AsW);
        gld_lds16(Ag + kb + 64 * 2048, AsW + 4096);
        gld_lds16(Bg + kb,             BsW);
        gld_lds16(Bg + kb + 64 * 2048, BsW + 4096);
        __syncthreads();
        bf16x8 af[4], bfv[4];
#pragma unroll
        for (int mt = 0; mt < 4; ++mt)
            af[mt] = *(const bf16x8*)((const char*)As + aoff + mt * 1024);
#pragma unroll
        for (int nt = 0; nt < 4; ++nt)
            bfv[nt] = *(const bf16x8*)((const char*)Bs + boff + nt * 1024);
#pragma unroll
        for (int mt = 0; mt < 4; ++mt)
#pragma unroll
            for (int nt = 0; nt < 4; ++nt)
                acc[mt][nt] = __builtin_amdgcn_mfma_f32_16x16x32_bf16(af[mt], bfv[nt], acc[mt][nt], 0, 0, 0);
    }

    // epilogue: C/D layout col = lane&15, row = quad*4 + reg.
    const int col0 = tn * 128 + wc * 64 + m;
    const int row00 = tm * 128 + wr * 64 + quad * 4;
#pragma unroll
    for (int mt = 0; mt < 4; ++mt) {
        float ps0 = 0.f, ps1 = 0.f, ps2 = 0.f, ps3 = 0.f;
#pragma unroll
        for (int nt = 0; nt < 4; ++nt) {
            const int c = col0 + nt * 16;
            const float bb = (c < 1000) ? b2[c] : 0.0f;
            const float wf = (c < 1000) ? Wf[c] : 0.0f;
            ps0 += fmaxf(acc[mt][nt][0] + bb, 0.f) * wf;
            ps1 += fmaxf(acc[mt][nt][1] + bb, 0.f) * wf;
            ps2 += fmaxf(acc[mt][nt][2] + bb, 0.f) * wf;
            ps3 += fmaxf(acc[mt][nt][3] + bb, 0.f) * wf;
        }
#pragma unroll
        for (int msk = 1; msk < 16; msk <<= 1) {
            ps0 += __shfl_xor(ps0, msk);
            ps1 += __shfl_xor(ps1, msk);
            ps2 += __shfl_xor(ps2, msk);
            ps3 += __shfl_xor(ps3, msk);
        }
        if (m == 0) {
            const int row = row00 + mt * 16;
            if (row + 0 < NN) atomicAdd(&logits[row + 0], ps0);
            if (row + 1 < NN) atomicAdd(&logits[row + 1], ps1);
            if (row + 2 < NN) atomicAdd(&logits[row + 2], ps2);
            if (row + 3 < NN) atomicAdd(&logits[row + 3], ps3);
        }
    }
}

// masked segment softmax; batch sorted -> binary-search graph range; mask format
// detected in-block (int32 {0,1} / float32 {0,1.0f} / byte). bf bias dropped
// (uniform per-graph shift cancels in softmax).
__global__ __launch_bounds__(256) void softmax_kernel(const float* __restrict__ logits,
        const void* __restrict__ mask, const int* __restrict__ batch,
        float* __restrict__ out) {
    const int g = blockIdx.x;
    const int t = threadIdx.x;
    __shared__ int s_lo, s_hi, sf0, sf1;
    __shared__ float red[4];
    __shared__ float sval;
    if (t == 0) {
        sf0 = 0; sf1 = 0;
        int lo = 0, hi = NN;
        while (lo < hi) { const int mid = (lo + hi) >> 1; if (batch[mid] < g) lo = mid + 1; else hi = mid; }
        s_lo = lo;
        int lo2 = lo, hi2 = NN;
        while (lo2 < hi2) { const int mid = (lo2 + hi2) >> 1; if (batch[mid] < g + 1) lo2 = mid + 1; else hi2 = mid; }
        s_hi = lo2;
    }
    __syncthreads();
    for (int i = t; i < 5000; i += 256) {       // mask format probe (first 20000 B)
        const unsigned v = ((const unsigned*)mask)[i];
        if (v > 1u) atomicOr(&sf0, 1);
        if (v != 0u && v != 0x3F800000u) atomicOr(&sf1, 1);
    }
    __syncthreads();
    const int lo = s_lo, hi = s_hi;
    const int f0 = sf0, f1 = sf1;
    auto mget = [&](int i) -> int {
        if (f0 == 0) return ((const int*)mask)[i] != 0;
        if (f1 == 0) return ((const unsigned*)mask)[i] != 0u;
        return ((const unsigned char*)mask)[i] != 0;
    };
    float mx = -1e30f;
    for (int i = lo + t; i < hi; i += 256)
        if (mget(i)) mx = fmaxf(mx, logits[i]);
    for (int off = 32; off; off >>= 1) mx = fmaxf(mx, __shfl_down(mx, off));
    if ((t & 63) == 0) red[t >> 6] = mx;
    __syncthreads();
    if (t == 0) sval = fmaxf(fmaxf(red[0], red[1]), fmaxf(red[2], red[3]));
    __syncthreads();
    mx = sval;
    __syncthreads();
    float sm = 0.f;
    for (int i = lo + t; i < hi; i += 256)
        if (mget(i)) sm += expf(logits[i] - mx);
    for (int off = 32; off; off >>= 1) sm += __shfl_down(sm, off);
    if ((t & 63) == 0) red[t >> 6] = sm;
    __syncthreads();
    if (t == 0) sval = red[0] + red[1] + red[2] + red[3];
    __syncthreads();
    const float inv = 1.0f / fmaxf(sval, 1e-16f);
    for (int i = lo + t; i < hi; i += 256)
        out[i] = mget(i) ? expf(logits[i] - mx) * inv : 0.0f;
}

extern "C" void kernel_launch(void* const* d_in, const int* in_sizes, int n_in,
                              void* d_out, int out_size, void* d_ws, size_t ws_size,
                              hipStream_t stream) {
    (void)in_sizes; (void)n_in; (void)out_size; (void)ws_size;
    const float* x   = (const float*)d_in[0];
    const float* ew  = (const float*)d_in[1];
    const float* W1  = (const float*)d_in[2];
    const float* b1  = (const float*)d_in[3];
    const float* W2  = (const float*)d_in[4];
    const float* b2  = (const float*)d_in[5];
    const float* Wf  = (const float*)d_in[6];
    const int*   ei  = (const int*)d_in[8];
    const void*  mask  = d_in[9];
    const int*   batch = (const int*)d_in[10];
    float* out = (float*)d_out;

    char* p = (char*)d_ws;
    auto carve = [&](size_t bytes) { char* q = p; p += (bytes + 255) & ~(size_t)255; return q; };
    // zero-region (single hipMemsetAsync): deg, cnt, cursor, logits, Ax
    char* zbase = p;
    float* deg    = (float*)carve(NN * 4);
    int*   cnt    = (int*)carve(NN * 4);
    int*   cursor = (int*)carve(NN * 4);
    float* logits = (float*)carve(NN * 4);
    float* Ax     = (float*)carve(NN * 5 * 4);
    size_t zspan = (size_t)(p - zbase);
    int*   offs   = (int*)carve(NN * 4);
    float* dinv   = (float*)carve(NN * 4);
    int*   ssrc   = (int*)carve(NE * 4);
    float* snorm  = (float*)carve(NE * 4);
    unsigned short* W2t = (unsigned short*)carve((size_t)KP * KP * 2);
    unsigned short* h1  = (unsigned short*)carve((size_t)NN * KP * 2);
    unsigned short* G   = (unsigned short*)carve((size_t)MPAD2 * KP * 2);

    hipMemsetAsync(zbase, 0, zspan, stream);
    hipLaunchKernelGGL(deg_cnt_kernel,    dim3(625),   dim3(256),  0, stream, ei, ew, deg, cnt);
    hipLaunchKernelGGL(scan_kernel,       dim3(1),     dim3(1024), 0, stream, cnt, deg, offs, dinv);
    hipLaunchKernelGGL(scatter_ax_kernel, dim3(625),   dim3(256),  0, stream, ei, ew, dinv, offs, cursor, ssrc, snorm, x, Ax);
    hipLaunchKernelGGL(prep_kernel,       dim3(2274),  dim3(256),  0, stream, Ax, x, dinv, W1, b1, h1, W2, W2t);
    hipLaunchKernelGGL(agg1k_kernel,      dim3(MPAD2), dim3(256),  0, stream, h1, ssrc, snorm, offs, cnt, dinv, G);
    hipLaunchKernelGGL(gemm_kernel,       dim3(MT2*8), dim3(256),  0, stream, G, W2t, b2, Wf, logits);
    hipLaunchKernelGGL(softmax_kernel,    dim3(NG),    dim3(256),  0, stream, logits, mask, batch, out);
}

// Round 7
// 269.351 us; speedup vs baseline: 1.7434x; 1.2486x over previous
//
#include <hip/hip_runtime.h>

#define NN 20000
#define NE 160000
#define NG 16
#define KP 1024            // padded feature dim
#define MT2 160            // max M strips of 128 in compact space
#define MPAD2 (MT2*128)    // 20480

typedef __attribute__((ext_vector_type(8))) short bf16x8;
typedef __attribute__((ext_vector_type(4))) float f32x4;

#define GAS __attribute__((address_space(1)))
#define LAS __attribute__((address_space(3)))

__device__ __forceinline__ unsigned short f2bf(float f) {
    unsigned int u = __float_as_uint(f);
    u += 0x7FFFu + ((u >> 16) & 1u);   // round-to-nearest-even
    return (unsigned short)(u >> 16);
}

__device__ __forceinline__ float bf2f(unsigned short u) {
    return __uint_as_float(((unsigned)u) << 16);
}

__device__ __forceinline__ void gld_lds16(const char* g, char* l) {
    __builtin_amdgcn_global_load_lds((GAS void*)g, (LAS void*)l, 16, 0, 0);
}

// deg/cnt/cursor/logitsC/flags zeroed by hipMemsetAsync before this.
// Also probes the mask bit-format (int32 {0,1} / float32 {0,1.0f} / byte).
__global__ void deg_cnt_kernel(const int* __restrict__ ei, const float* __restrict__ ew,
                               float* deg, int* cnt, const void* __restrict__ mask,
                               int* flags) {
    const int e = blockIdx.x * blockDim.x + threadIdx.x;
    if (e < 5000) {
        const unsigned v = ((const unsigned*)mask)[e];
        if (v > 1u) atomicOr(&flags[0], 1);                      // not int32 {0,1}
        if (v != 0u && v != 0x3F800000u) atomicOr(&flags[1], 1); // not float32 {0,1.0f}
    }
    if (e >= NE) return;
    const int c = ei[NE + e];
    atomicAdd(&deg[c], ew[e]);
    atomicAdd(&cnt[c], 1);
}

// One block: edge-count scan -> offs, dinv (self-loop folded), and mask scan ->
// perm (compact masked-node list), bc (graph id per compact slot), nm (count).
__global__ __launch_bounds__(1024) void scan_kernel(const int* __restrict__ cnt,
        const float* __restrict__ deg, const void* __restrict__ mask,
        const int* __restrict__ flags, const int* __restrict__ batch,
        int* __restrict__ offs, float* __restrict__ dinv,
        int* __restrict__ perm, int* __restrict__ bc, int* __restrict__ nm) {
    __shared__ int part[1024];
    __shared__ int partm[1024];
    const int t = threadIdx.x;
    const int base = t * 20;   // 1024*20 >= 20000
    const int f0 = flags[0], f1 = flags[1];
    int s = 0, sm = 0;
    unsigned mbits = 0;
    for (int j = 0; j < 20; ++j) {
        const int i = base + j;
        if (i < NN) {
            s += cnt[i];
            dinv[i] = 1.0f / sqrtf(2.0f + deg[i]);   // always > 0
            int mv;
            if (f0 == 0)      mv = ((const int*)mask)[i] != 0;
            else if (f1 == 0) mv = ((const unsigned*)mask)[i] != 0u;
            else              mv = ((const unsigned char*)mask)[i] != 0;
            mbits |= (unsigned)mv << j;
            sm += mv;
        }
    }
    part[t] = s; partm[t] = sm;
    __syncthreads();
    for (int off = 1; off < 1024; off <<= 1) {
        const int u  = (t >= off) ? part[t - off]  : 0;
        const int um = (t >= off) ? partm[t - off] : 0;
        __syncthreads();
        part[t] += u; partm[t] += um;
        __syncthreads();
    }
    int run  = part[t] - s;    // exclusive prefixes for this thread's chunk
    int runm = partm[t] - sm;
    for (int j = 0; j < 20; ++j) {
        const int i = base + j;
        if (i < NN) {
            offs[i] = run; run += cnt[i];
            if ((mbits >> j) & 1u) { perm[runm] = i; bc[runm] = batch[i]; ++runm; }
        }
    }
    if (t == 1023) nm[0] = partm[1023];
}

__global__ void scatter_kernel(const int* __restrict__ ei, const float* __restrict__ ew,
                               const float* __restrict__ dinv, const int* __restrict__ offs,
                               int* cursor, int* __restrict__ ssrc, float* __restrict__ snorm) {
    const int e = blockIdx.x * blockDim.x + threadIdx.x;
    if (e >= NE) return;
    const int r = ei[e], c = ei[NE + e];
    const int pos = atomicAdd(&cursor[c], 1);
    const int idx = offs[c] + pos;
    ssrc[idx] = r;
    snorm[idx] = dinv[r] * ew[e] * dinv[c];
}

// Ax = A_norm * x  (5-wide gather; self-loop added in prep)
__global__ __launch_bounds__(256) void ax_kernel(const float* __restrict__ x,
        const int* __restrict__ ssrc, const float* __restrict__ snorm,
        const int* __restrict__ offs, const int* __restrict__ cnt,
        float* __restrict__ Ax) {
    const int i = blockIdx.x * blockDim.x + threadIdx.x;
    if (i >= NN) return;
    float a0=0,a1=0,a2=0,a3=0,a4=0;
    const int s0 = offs[i], n = cnt[i];
    for (int e = s0; e < s0 + n; ++e) {
        const int r = ssrc[e];
        const float w = snorm[e];
        const float* xr = x + r * 5;
        a0 += w*xr[0]; a1 += w*xr[1]; a2 += w*xr[2]; a3 += w*xr[3]; a4 += w*xr[4];
    }
    float* o = Ax + i * 5;
    o[0]=a0; o[1]=a1; o[2]=a2; o[3]=a3; o[4]=a4;
}

// prep = layer1 (blocks 0..1249, 16 nodes each, W1 in LDS; self-loop folded into
// the Ax read) + W2 transpose (blocks 1250..2273).
__global__ __launch_bounds__(256) void prep_kernel(const float* __restrict__ Ax,
        const float* __restrict__ x, const float* __restrict__ dinv,
        const float* __restrict__ W1, const float* __restrict__ b1,
        unsigned short* __restrict__ h1,
        const float* __restrict__ W2, unsigned short* __restrict__ W2t) {
    const int bid = blockIdx.x;
    const int t = threadIdx.x;
    if (bid < 1250) {
        __shared__ float w1s[5000];
        __shared__ float axs[80];
        for (int idx = t; idx < 1250; idx += 256)
            ((float4*)w1s)[idx] = ((const float4*)W1)[idx];
        const int nb = bid * 16;
        if (t < 80) {
            const int node = nb + t / 5;
            const float dv = dinv[node];
            axs[t] = Ax[nb * 5 + t] + 2.0f * dv * dv * x[nb * 5 + t];
        }
        __syncthreads();
        if (t < 250) {
            const int c0 = t * 4;
            float w[5][4];
#pragma unroll
            for (int f = 0; f < 5; ++f) {
                const float4 wv = ((const float4*)w1s)[f * 250 + t];
                w[f][0] = wv.x; w[f][1] = wv.y; w[f][2] = wv.z; w[f][3] = wv.w;
            }
            const float4 bb = *(const float4*)(b1 + c0);
            for (int n = 0; n < 16; ++n) {
                float r0 = bb.x, r1 = bb.y, r2 = bb.z, r3 = bb.w;
#pragma unroll
                for (int f = 0; f < 5; ++f) {
                    const float av = axs[n * 5 + f];
                    r0 += av * w[f][0]; r1 += av * w[f][1];
                    r2 += av * w[f][2]; r3 += av * w[f][3];
                }
                ushort4 pk;
                pk.x = f2bf(fmaxf(r0, 0.f)); pk.y = f2bf(fmaxf(r1, 0.f));
                pk.z = f2bf(fmaxf(r2, 0.f)); pk.w = f2bf(fmaxf(r3, 0.f));
                *(ushort4*)(h1 + (size_t)(nb + n) * KP + c0) = pk;
            }
        } else {
            const int c0 = 1000 + (t - 250) * 4;   // zero pad cols 1000..1023
            ushort4 zz = {0, 0, 0, 0};
            for (int n = 0; n < 16; ++n)
                *(ushort4*)(h1 + (size_t)(nb + n) * KP + c0) = zz;
        }
    } else {
        __shared__ float tile[32][33];
        const int bw = bid - 1250;
        const int n0 = (bw & 31) * 32;
        const int k0 = (bw >> 5) * 32;
        const int tx = t & 31, ty = t >> 5;        // 32 x 8
#pragma unroll
        for (int j = 0; j < 4; ++j) {
            const int k = k0 + ty + j * 8;
            const int n = n0 + tx;
            tile[ty + j * 8][tx] = (k < 1000 && n < 1000) ? W2[k * 1000 + n] : 0.0f;
        }
        __syncthreads();
#pragma unroll
        for (int j = 0; j < 4; ++j) {
            const int n = n0 + ty + j * 8;
            const int k = k0 + tx;
            W2t[(size_t)n * KP + k] = f2bf(tile[tx][ty + j * 8]);
        }
    }
}

// G[j] = (A_norm * h1)[perm[j]] for compact slot j < nm; rows [nm, pad128(nm))
// zeroed; blocks beyond that exit. Edge meta staged in LDS (64-edge chunks);
// 2 parities x 2-deep unroll.
__global__ __launch_bounds__(256) void agg1k_kernel(const unsigned short* __restrict__ h1,
        const int* __restrict__ ssrc, const float* __restrict__ snorm,
        const int* __restrict__ offs, const int* __restrict__ cnt,
        const float* __restrict__ dinv, const int* __restrict__ perm,
        const int* __restrict__ nm, unsigned short* __restrict__ G) {
    const int j0 = blockIdx.x;
    const int t = threadIdx.x;
    __shared__ int s_nm;
    if (t == 0) s_nm = nm[0];
    __syncthreads();
    const int nmv = s_nm;
    const int npad = (nmv + 127) & ~127;
    if (j0 >= npad) return;
    const int sub = t >> 7;          // 0/1: edge parity
    const int tc = t & 127;          // col group: cols [tc*8, tc*8+8)
    unsigned short* grow = G + (size_t)j0 * KP + tc * 8;
    if (j0 >= nmv) {
        if (sub == 0) {
            bf16x8 z = {0,0,0,0,0,0,0,0};
            *(bf16x8*)grow = z;
        }
        return;
    }
    const int i = perm[j0];
    __shared__ int   se[64];
    __shared__ float sw[64];
    float acc[8] = {0,0,0,0,0,0,0,0};
    float acc2[8] = {0,0,0,0,0,0,0,0};
    const int s0 = offs[i], n = cnt[i];
    for (int base = 0; base < n; base += 64) {
        const int m = (n - base < 64) ? (n - base) : 64;
        __syncthreads();
        if (t < m) { se[t] = ssrc[s0 + base + t]; sw[t] = snorm[s0 + base + t]; }
        __syncthreads();
        int e = sub;
        for (; e + 2 < m; e += 4) {       // two independent load+acc chains
            const int r0 = se[e];     const float w0 = sw[e];
            const int r1 = se[e + 2]; const float w1 = sw[e + 2];
            const bf16x8 v0 = *(const bf16x8*)(h1 + (size_t)r0 * KP + tc * 8);
            const bf16x8 v1 = *(const bf16x8*)(h1 + (size_t)r1 * KP + tc * 8);
#pragma unroll
            for (int jj = 0; jj < 8; ++jj) acc[jj]  += w0 * bf2f((unsigned short)v0[jj]);
#pragma unroll
            for (int jj = 0; jj < 8; ++jj) acc2[jj] += w1 * bf2f((unsigned short)v1[jj]);
        }
        for (; e < m; e += 2) {
            const int r = se[e];
            const float w = sw[e];
            const bf16x8 hv = *(const bf16x8*)(h1 + (size_t)r * KP + tc * 8);
#pragma unroll
            for (int jj = 0; jj < 8; ++jj) acc[jj] += w * bf2f((unsigned short)hv[jj]);
        }
    }
    if (sub == 0) {
        const float wl = 2.0f * dinv[i] * dinv[i];
        const bf16x8 hv = *(const bf16x8*)(h1 + (size_t)i * KP + tc * 8);
#pragma unroll
        for (int jj = 0; jj < 8; ++jj) acc[jj] += wl * bf2f((unsigned short)hv[jj]);
    }
#pragma unroll
    for (int jj = 0; jj < 8; ++jj) acc[jj] += acc2[jj];
    __shared__ float red[128][8];
    if (sub == 1) {
#pragma unroll
        for (int jj = 0; jj < 8; ++jj) red[tc][jj] = acc[jj];
    }
    __syncthreads();
    if (sub == 0) {
        bf16x8 o;
#pragma unroll
        for (int jj = 0; jj < 8; ++jj) o[jj] = (short)f2bf(acc[jj] + red[tc][jj]);
        *(bf16x8*)grow = o;
    }
}

// logitsC[row] += sum_cols relu(G @ W2 + b2) * Wf over compact rows < nm.
// 128x128 tile / BK=32 / width-16 global_load_lds / XOR-swizzled LDS.
// tm=(bid>>6)*8+(bid&7), tn=(bid>>3)&7: id%8==tm%8 -> A-strip's 8 readers share
// an XCD (FETCH 163->33 MB measured R6). Blocks with tm >= active strips exit.
__global__ __launch_bounds__(256) void gemm_kernel(const unsigned short* __restrict__ A,
                                                   const unsigned short* __restrict__ B,
                                                   const float* __restrict__ b2,
                                                   const float* __restrict__ Wf,
                                                   const int* __restrict__ nm,
                                                   float* __restrict__ logitsC) {
    __shared__ unsigned short As[4096];  // 128 rows x 32 k (bf16) = 8 KB
    __shared__ unsigned short Bs[4096];
    const int tid = threadIdx.x;
    __shared__ int s_nm;
    if (tid == 0) s_nm = nm[0];
    __syncthreads();
    const int nmv = s_nm;
    const int mstrips = (nmv + 127) >> 7;
    const int bid = blockIdx.x;
    const int tm = (bid >> 6) * 8 + (bid & 7);   // 0..159, tm%8 == bid%8
    const int tn = (bid >> 3) & 7;
    if (tm >= mstrips) return;
    const int lane = tid & 63;
    const int wv = tid >> 6;
    const int wr = wv >> 1, wc = wv & 1;

    const int chunk = ((tid & 3) ^ ((tid >> 3) & 3)) * 16;
    const int rsub = tid >> 2;   // row 0..63 (+64 in round 1)
    const char* Ag = (const char*)(A + (size_t)(tm * 128 + rsub) * KP) + chunk;
    const char* Bg = (const char*)(B + (size_t)(tn * 128 + rsub) * KP) + chunk;
    char* AsW = (char*)As + wv * 1024;
    char* BsW = (char*)Bs + wv * 1024;

    f32x4 acc[4][4];
#pragma unroll
    for (int i = 0; i < 4; ++i)
#pragma unroll
        for (int j = 0; j < 4; ++j) acc[i][j] = (f32x4){0.f, 0.f, 0.f, 0.f};

    const int m = lane & 15;
    const int quad = lane >> 4;
    const int sw = quad ^ ((m >> 1) & 3);       // swizzled k-chunk slot
    const int aoff = (wr * 64 + m) * 64 + sw * 16;
    const int boff = (wc * 64 + m) * 64 + sw * 16;

    for (int kk = 0; kk < KP; kk += 32) {
        __syncthreads();
        const int kb = kk * 2;
        gld_lds16(Ag + kb,             AsW);
        gld_lds16(Ag + kb + 64 * 2048, AsW + 4096);
        gld_lds16(Bg + kb,             BsW);
        gld_lds16(Bg + kb + 64 * 2048, BsW + 4096);
        __syncthreads();
        bf16x8 af[4], bfv[4];
#pragma unroll
        for (int mt = 0; mt < 4; ++mt)
            af[mt] = *(const bf16x8*)((const char*)As + aoff + mt * 1024);
#pragma unroll
        for (int nt = 0; nt < 4; ++nt)
            bfv[nt] = *(const bf16x8*)((const char*)Bs + boff + nt * 1024);
#pragma unroll
        for (int mt = 0; mt < 4; ++mt)
#pragma unroll
            for (int nt = 0; nt < 4; ++nt)
                acc[mt][nt] = __builtin_amdgcn_mfma_f32_16x16x32_bf16(af[mt], bfv[nt], acc[mt][nt], 0, 0, 0);
    }

    // epilogue: C/D layout col = lane&15, row = quad*4 + reg
    const int col0 = tn * 128 + wc * 64 + m;
    const int row00 = tm * 128 + wr * 64 + quad * 4;
#pragma unroll
    for (int mt = 0; mt < 4; ++mt) {
        float ps0 = 0.f, ps1 = 0.f, ps2 = 0.f, ps3 = 0.f;
#pragma unroll
        for (int nt = 0; nt < 4; ++nt) {
            const int c = col0 + nt * 16;
            const float bb = (c < 1000) ? b2[c] : 0.0f;
            const float wf = (c < 1000) ? Wf[c] : 0.0f;
            ps0 += fmaxf(acc[mt][nt][0] + bb, 0.f) * wf;
            ps1 += fmaxf(acc[mt][nt][1] + bb, 0.f) * wf;
            ps2 += fmaxf(acc[mt][nt][2] + bb, 0.f) * wf;
            ps3 += fmaxf(acc[mt][nt][3] + bb, 0.f) * wf;
        }
#pragma unroll
        for (int msk = 1; msk < 16; msk <<= 1) {
            ps0 += __shfl_xor(ps0, msk);
            ps1 += __shfl_xor(ps1, msk);
            ps2 += __shfl_xor(ps2, msk);
            ps3 += __shfl_xor(ps3, msk);
        }
        if (m == 0) {
            const int row = row00 + mt * 16;
            if (row + 0 < nmv) atomicAdd(&logitsC[row + 0], ps0);
            if (row + 1 < nmv) atomicAdd(&logitsC[row + 1], ps1);
            if (row + 2 < nmv) atomicAdd(&logitsC[row + 2], ps2);
            if (row + 3 < nmv) atomicAdd(&logitsC[row + 3], ps3);
        }
    }
}

// segment softmax over compact (all-masked) logits; bc sorted -> binary search.
// out pre-zeroed by memset; only masked slots written via perm.
__global__ __launch_bounds__(256) void softmax_kernel(const float* __restrict__ logitsC,
        const int* __restrict__ perm, const int* __restrict__ bc,
        const int* __restrict__ nm, float* __restrict__ out) {
    const int g = blockIdx.x;
    const int t = threadIdx.x;
    __shared__ int s_lo, s_hi;
    __shared__ float red[4];
    __shared__ float sval;
    if (t == 0) {
        const int nmv = nm[0];
        int lo = 0, hi = nmv;
        while (lo < hi) { const int mid = (lo + hi) >> 1; if (bc[mid] < g) lo = mid + 1; else hi = mid; }
        s_lo = lo;
        int lo2 = lo, hi2 = nmv;
        while (lo2 < hi2) { const int mid = (lo2 + hi2) >> 1; if (bc[mid] < g + 1) lo2 = mid + 1; else hi2 = mid; }
        s_hi = lo2;
    }
    __syncthreads();
    const int lo = s_lo, hi = s_hi;
    float mx = -1e30f;
    for (int i = lo + t; i < hi; i += 256) mx = fmaxf(mx, logitsC[i]);
    for (int off = 32; off; off >>= 1) mx = fmaxf(mx, __shfl_down(mx, off));
    if ((t & 63) == 0) red[t >> 6] = mx;
    __syncthreads();
    if (t == 0) sval = fmaxf(fmaxf(red[0], red[1]), fmaxf(red[2], red[3]));
    __syncthreads();
    mx = sval;
    __syncthreads();
    float sm = 0.f;
    for (int i = lo + t; i < hi; i += 256) sm += expf(logitsC[i] - mx);
    for (int off = 32; off; off >>= 1) sm += __shfl_down(sm, off);
    if ((t & 63) == 0) red[t >> 6] = sm;
    __syncthreads();
    if (t == 0) sval = red[0] + red[1] + red[2] + red[3];
    __syncthreads();
    const float inv = 1.0f / fmaxf(sval, 1e-16f);
    for (int i = lo + t; i < hi; i += 256)
        out[perm[i]] = expf(logitsC[i] - mx) * inv;
}

extern "C" void kernel_launch(void* const* d_in, const int* in_sizes, int n_in,
                              void* d_out, int out_size, void* d_ws, size_t ws_size,
                              hipStream_t stream) {
    (void)in_sizes; (void)n_in; (void)ws_size;
    const float* x   = (const float*)d_in[0];
    const float* ew  = (const float*)d_in[1];
    const float* W1  = (const float*)d_in[2];
    const float* b1  = (const float*)d_in[3];
    const float* W2  = (const float*)d_in[4];
    const float* b2  = (const float*)d_in[5];
    const float* Wf  = (const float*)d_in[6];
    const int*   ei  = (const int*)d_in[8];
    const void*  mask  = d_in[9];
    const int*   batch = (const int*)d_in[10];
    float* out = (float*)d_out;

    char* p = (char*)d_ws;
    auto carve = [&](size_t bytes) { char* q = p; p += (bytes + 255) & ~(size_t)255; return q; };
    // zero-region (single hipMemsetAsync): deg, cnt, cursor, logitsC, flags
    char* zbase = p;
    float* deg     = (float*)carve(NN * 4);
    int*   cnt     = (int*)carve(NN * 4);
    int*   cursor  = (int*)carve(NN * 4);
    float* logitsC = (float*)carve(MPAD2 * 4);
    int*   flags   = (int*)carve(256);
    size_t zspan = (size_t)(p - zbase);
    int*   offs   = (int*)carve(NN * 4);
    float* dinv   = (float*)carve(NN * 4);
    int*   perm   = (int*)carve(NN * 4);
    int*   bc     = (int*)carve(NN * 4);
    int*   nmp    = (int*)carve(256);
    int*   ssrc   = (int*)carve(NE * 4);
    float* snorm  = (float*)carve(NE * 4);
    float* Ax     = (float*)carve(NN * 5 * 4);
    unsigned short* W2t = (unsigned short*)carve((size_t)KP * KP * 2);
    unsigned short* h1  = (unsigned short*)carve((size_t)NN * KP * 2);
    unsigned short* G   = (unsigned short*)carve((size_t)MPAD2 * KP * 2);

    hipMemsetAsync(zbase, 0, zspan, stream);
    hipMemsetAsync(out, 0, (size_t)out_size * 4, stream);
    hipLaunchKernelGGL(deg_cnt_kernel, dim3(625),   dim3(256),  0, stream, ei, ew, deg, cnt, mask, flags);
    hipLaunchKernelGGL(scan_kernel,    dim3(1),     dim3(1024), 0, stream, cnt, deg, mask, flags, batch, offs, dinv, perm, bc, nmp);
    hipLaunchKernelGGL(scatter_kernel, dim3(625),   dim3(256),  0, stream, ei, ew, dinv, offs, cursor, ssrc, snorm);
    hipLaunchKernelGGL(ax_kernel,      dim3(79),    dim3(256),  0, stream, x, ssrc, snorm, offs, cnt, Ax);
    hipLaunchKernelGGL(prep_kernel,    dim3(2274),  dim3(256),  0, stream, Ax, x, dinv, W1, b1, h1, W2, W2t);
    hipLaunchKernelGGL(agg1k_kernel,   dim3(MPAD2), dim3(256),  0, stream, h1, ssrc, snorm, offs, cnt, dinv, perm, nmp, G);
    hipLaunchKernelGGL(gemm_kernel,    dim3(MT2*8), dim3(256),  0, stream, G, W2t, b2, Wf, nmp, logitsC);
    hipLaunchKernelGGL(softmax_kernel, dim3(NG),    dim3(256),  0, stream, logitsC, perm, bc, nmp, out);
}

// Round 8
// 205.490 us; speedup vs baseline: 2.2852x; 1.3108x over previous
//
#include <hip/hip_runtime.h>

#define NN 20000
#define NE 160000
#define NG 16
#define KP 1024            // padded feature dim
#define MT2 160            // max M strips of 128 in compact space
#define MPAD2 (MT2*128)    // 20480
#define NBLK 79            // ceil(20000/256)

typedef __attribute__((ext_vector_type(8))) short bf16x8;
typedef __attribute__((ext_vector_type(4))) float f32x4;

#define GAS __attribute__((address_space(1)))
#define LAS __attribute__((address_space(3)))

__device__ __forceinline__ unsigned short f2bf(float f) {
    unsigned int u = __float_as_uint(f);
    u += 0x7FFFu + ((u >> 16) & 1u);   // round-to-nearest-even
    return (unsigned short)(u >> 16);
}

__device__ __forceinline__ float bf2f(unsigned short u) {
    return __uint_as_float(((unsigned)u) << 16);
}

__device__ __forceinline__ void gld_lds16(const char* g, char* l) {
    __builtin_amdgcn_global_load_lds((GAS void*)g, (LAS void*)l, 16, 0, 0);
}

// deg/cnt/cursor/logitsC/flags zeroed by hipMemsetAsync before this.
// Also probes the mask bit-format (int32 {0,1} / float32 {0,1.0f} / byte).
__global__ void deg_cnt_kernel(const int* __restrict__ ei, const float* __restrict__ ew,
                               float* deg, int* cnt, const void* __restrict__ mask,
                               int* flags) {
    const int e = blockIdx.x * blockDim.x + threadIdx.x;
    if (e < 5000) {
        const unsigned v = ((const unsigned*)mask)[e];
        if (v > 1u) atomicOr(&flags[0], 1);                      // not int32 {0,1}
        if (v != 0u && v != 0x3F800000u) atomicOr(&flags[1], 1); // not float32 {0,1.0f}
    }
    if (e >= NE) return;
    const int c = ei[NE + e];
    atomicAdd(&deg[c], ew[e]);
    atomicAdd(&cnt[c], 1);
}

// ---- parallel scan, phase 1: per-block sums (edge counts + mask), dinv, mask decode
__global__ __launch_bounds__(256) void partial_kernel(const int* __restrict__ cnt,
        const float* __restrict__ deg, const void* __restrict__ mask,
        const int* __restrict__ flags, int* __restrict__ mtmp,
        float* __restrict__ dinv, int* __restrict__ bcnt, int* __restrict__ bmsk) {
    const int b = blockIdx.x, t = threadIdx.x;
    const int i = b * 256 + t;
    const int f0 = flags[0], f1 = flags[1];
    int c = 0, mv = 0;
    if (i < NN) {
        c = cnt[i];
        dinv[i] = 1.0f / sqrtf(2.0f + deg[i]);   // self-loop weight 2 folded; > 0
        if (f0 == 0)      mv = ((const int*)mask)[i] != 0;
        else if (f1 == 0) mv = ((const unsigned*)mask)[i] != 0u;
        else              mv = ((const unsigned char*)mask)[i] != 0;
        mtmp[i] = mv;
    }
    __shared__ int sc[256], sm[256];
    sc[t] = c; sm[t] = mv;
    __syncthreads();
    for (int off = 128; off; off >>= 1) {
        if (t < off) { sc[t] += sc[t + off]; sm[t] += sm[t + off]; }
        __syncthreads();
    }
    if (t == 0) { bcnt[b] = sc[0]; bmsk[b] = sm[0]; }
}

// ---- phase 2: exclusive scan of the NBLK partials (one tiny block) + nm
__global__ __launch_bounds__(128) void scanp_kernel(int* __restrict__ bcnt,
        int* __restrict__ bmsk, int* __restrict__ nm) {
    const int t = threadIdx.x;
    __shared__ int sc[128], sm[128];
    const int c = (t < NBLK) ? bcnt[t] : 0;
    const int m = (t < NBLK) ? bmsk[t] : 0;
    sc[t] = c; sm[t] = m;
    __syncthreads();
    for (int off = 1; off < 128; off <<= 1) {
        const int uc = (t >= off) ? sc[t - off] : 0;
        const int um = (t >= off) ? sm[t - off] : 0;
        __syncthreads();
        sc[t] += uc; sm[t] += um;
        __syncthreads();
    }
    if (t < NBLK) { bcnt[t] = sc[t] - c; bmsk[t] = sm[t] - m; }   // exclusive
    if (t == NBLK - 1) nm[0] = sm[t];
}

// ---- phase 3: in-block scan + block offset -> offs, perm, bc
__global__ __launch_bounds__(256) void apply_kernel(const int* __restrict__ cnt,
        const int* __restrict__ mtmp, const int* __restrict__ bcnt,
        const int* __restrict__ bmsk, const int* __restrict__ batch,
        int* __restrict__ offs, int* __restrict__ perm, int* __restrict__ bc) {
    const int b = blockIdx.x, t = threadIdx.x;
    const int i = b * 256 + t;
    const int c  = (i < NN) ? cnt[i]  : 0;
    const int mv = (i < NN) ? mtmp[i] : 0;
    __shared__ int sc[256], sm[256];
    sc[t] = c; sm[t] = mv;
    __syncthreads();
    for (int off = 1; off < 256; off <<= 1) {
        const int uc = (t >= off) ? sc[t - off] : 0;
        const int um = (t >= off) ? sm[t - off] : 0;
        __syncthreads();
        sc[t] += uc; sm[t] += um;
        __syncthreads();
    }
    if (i < NN) {
        offs[i] = bcnt[b] + sc[t] - c;           // exclusive edge-count prefix
        if (mv) {
            const int pos = bmsk[b] + sm[t] - 1; // compact slot
            perm[pos] = i;
            bc[pos] = batch[i];
        }
    }
}

__global__ void scatter_kernel(const int* __restrict__ ei, const float* __restrict__ ew,
                               const float* __restrict__ dinv, const int* __restrict__ offs,
                               int* cursor, int* __restrict__ ssrc, float* __restrict__ snorm) {
    const int e = blockIdx.x * blockDim.x + threadIdx.x;
    if (e >= NE) return;
    const int r = ei[e], c = ei[NE + e];
    const int pos = atomicAdd(&cursor[c], 1);
    const int idx = offs[c] + pos;
    ssrc[idx] = r;
    snorm[idx] = dinv[r] * ew[e] * dinv[c];
}

// Ax = A_norm * x  (5-wide gather; self-loop added in prep)
__global__ __launch_bounds__(256) void ax_kernel(const float* __restrict__ x,
        const int* __restrict__ ssrc, const float* __restrict__ snorm,
        const int* __restrict__ offs, const int* __restrict__ cnt,
        float* __restrict__ Ax) {
    const int i = blockIdx.x * blockDim.x + threadIdx.x;
    if (i >= NN) return;
    float a0=0,a1=0,a2=0,a3=0,a4=0;
    const int s0 = offs[i], n = cnt[i];
    for (int e = s0; e < s0 + n; ++e) {
        const int r = ssrc[e];
        const float w = snorm[e];
        const float* xr = x + r * 5;
        a0 += w*xr[0]; a1 += w*xr[1]; a2 += w*xr[2]; a3 += w*xr[3]; a4 += w*xr[4];
    }
    float* o = Ax + i * 5;
    o[0]=a0; o[1]=a1; o[2]=a2; o[3]=a3; o[4]=a4;
}

// prep = layer1 (blocks 0..1249, 16 nodes each, W1 in LDS; self-loop folded into
// the Ax read) + W2 transpose (blocks 1250..2273).
__global__ __launch_bounds__(256) void prep_kernel(const float* __restrict__ Ax,
        const float* __restrict__ x, const float* __restrict__ dinv,
        const float* __restrict__ W1, const float* __restrict__ b1,
        unsigned short* __restrict__ h1,
        const float* __restrict__ W2, unsigned short* __restrict__ W2t) {
    const int bid = blockIdx.x;
    const int t = threadIdx.x;
    if (bid < 1250) {
        __shared__ float w1s[5000];
        __shared__ float axs[80];
        for (int idx = t; idx < 1250; idx += 256)
            ((float4*)w1s)[idx] = ((const float4*)W1)[idx];
        const int nb = bid * 16;
        if (t < 80) {
            const int node = nb + t / 5;
            const float dv = dinv[node];
            axs[t] = Ax[nb * 5 + t] + 2.0f * dv * dv * x[nb * 5 + t];
        }
        __syncthreads();
        if (t < 250) {
            const int c0 = t * 4;
            float w[5][4];
#pragma unroll
            for (int f = 0; f < 5; ++f) {
                const float4 wv = ((const float4*)w1s)[f * 250 + t];
                w[f][0] = wv.x; w[f][1] = wv.y; w[f][2] = wv.z; w[f][3] = wv.w;
            }
            const float4 bb = *(const float4*)(b1 + c0);
            for (int n = 0; n < 16; ++n) {
                float r0 = bb.x, r1 = bb.y, r2 = bb.z, r3 = bb.w;
#pragma unroll
                for (int f = 0; f < 5; ++f) {
                    const float av = axs[n * 5 + f];
                    r0 += av * w[f][0]; r1 += av * w[f][1];
                    r2 += av * w[f][2]; r3 += av * w[f][3];
                }
                ushort4 pk;
                pk.x = f2bf(fmaxf(r0, 0.f)); pk.y = f2bf(fmaxf(r1, 0.f));
                pk.z = f2bf(fmaxf(r2, 0.f)); pk.w = f2bf(fmaxf(r3, 0.f));
                *(ushort4*)(h1 + (size_t)(nb + n) * KP + c0) = pk;
            }
        } else {
            const int c0 = 1000 + (t - 250) * 4;   // zero pad cols 1000..1023
            ushort4 zz = {0, 0, 0, 0};
            for (int n = 0; n < 16; ++n)
                *(ushort4*)(h1 + (size_t)(nb + n) * KP + c0) = zz;
        }
    } else {
        __shared__ float tile[32][33];
        const int bw = bid - 1250;
        const int n0 = (bw & 31) * 32;
        const int k0 = (bw >> 5) * 32;
        const int tx = t & 31, ty = t >> 5;        // 32 x 8
#pragma unroll
        for (int j = 0; j < 4; ++j) {
            const int k = k0 + ty + j * 8;
            const int n = n0 + tx;
            tile[ty + j * 8][tx] = (k < 1000 && n < 1000) ? W2[k * 1000 + n] : 0.0f;
        }
        __syncthreads();
#pragma unroll
        for (int j = 0; j < 4; ++j) {
            const int n = n0 + ty + j * 8;
            const int k = k0 + tx;
            W2t[(size_t)n * KP + k] = f2bf(tile[tx][ty + j * 8]);
        }
    }
}

// G[j] = (A_norm * h1)[perm[j]] for compact slot j < nm; rows [nm, pad128(nm))
// zeroed; blocks beyond that exit. Edge meta staged in LDS (64-edge chunks);
// 2 parities x 2-deep unroll.
__global__ __launch_bounds__(256) void agg1k_kernel(const unsigned short* __restrict__ h1,
        const int* __restrict__ ssrc, const float* __restrict__ snorm,
        const int* __restrict__ offs, const int* __restrict__ cnt,
        const float* __restrict__ dinv, const int* __restrict__ perm,
        const int* __restrict__ nm, unsigned short* __restrict__ G) {
    const int j0 = blockIdx.x;
    const int t = threadIdx.x;
    __shared__ int s_nm;
    if (t == 0) s_nm = nm[0];
    __syncthreads();
    const int nmv = s_nm;
    const int npad = (nmv + 127) & ~127;
    if (j0 >= npad) return;
    const int sub = t >> 7;          // 0/1: edge parity
    const int tc = t & 127;          // col group: cols [tc*8, tc*8+8)
    unsigned short* grow = G + (size_t)j0 * KP + tc * 8;
    if (j0 >= nmv) {
        if (sub == 0) {
            bf16x8 z = {0,0,0,0,0,0,0,0};
            *(bf16x8*)grow = z;
        }
        return;
    }
    const int i = perm[j0];
    __shared__ int   se[64];
    __shared__ float sw[64];
    float acc[8] = {0,0,0,0,0,0,0,0};
    float acc2[8] = {0,0,0,0,0,0,0,0};
    const int s0 = offs[i], n = cnt[i];
    for (int base = 0; base < n; base += 64) {
        const int m = (n - base < 64) ? (n - base) : 64;
        __syncthreads();
        if (t < m) { se[t] = ssrc[s0 + base + t]; sw[t] = snorm[s0 + base + t]; }
        __syncthreads();
        int e = sub;
        for (; e + 2 < m; e += 4) {       // two independent load+acc chains
            const int r0 = se[e];     const float w0 = sw[e];
            const int r1 = se[e + 2]; const float w1 = sw[e + 2];
            const bf16x8 v0 = *(const bf16x8*)(h1 + (size_t)r0 * KP + tc * 8);
            const bf16x8 v1 = *(const bf16x8*)(h1 + (size_t)r1 * KP + tc * 8);
#pragma unroll
            for (int jj = 0; jj < 8; ++jj) acc[jj]  += w0 * bf2f((unsigned short)v0[jj]);
#pragma unroll
            for (int jj = 0; jj < 8; ++jj) acc2[jj] += w1 * bf2f((unsigned short)v1[jj]);
        }
        for (; e < m; e += 2) {
            const int r = se[e];
            const float w = sw[e];
            const bf16x8 hv = *(const bf16x8*)(h1 + (size_t)r * KP + tc * 8);
#pragma unroll
            for (int jj = 0; jj < 8; ++jj) acc[jj] += w * bf2f((unsigned short)hv[jj]);
        }
    }
    if (sub == 0) {
        const float wl = 2.0f * dinv[i] * dinv[i];
        const bf16x8 hv = *(const bf16x8*)(h1 + (size_t)i * KP + tc * 8);
#pragma unroll
        for (int jj = 0; jj < 8; ++jj) acc[jj] += wl * bf2f((unsigned short)hv[jj]);
    }
#pragma unroll
    for (int jj = 0; jj < 8; ++jj) acc[jj] += acc2[jj];
    __shared__ float red[128][8];
    if (sub == 1) {
#pragma unroll
        for (int jj = 0; jj < 8; ++jj) red[tc][jj] = acc[jj];
    }
    __syncthreads();
    if (sub == 0) {
        bf16x8 o;
#pragma unroll
        for (int jj = 0; jj < 8; ++jj) o[jj] = (short)f2bf(acc[jj] + red[tc][jj]);
        *(bf16x8*)grow = o;
    }
}

// logitsC[row] += sum_cols relu(G @ W2 + b2) * Wf over compact rows < nm.
// 128x128 tile / BK=32 / width-16 global_load_lds / XOR-swizzled LDS.
// tm=(bid>>6)*8+(bid&7), tn=(bid>>3)&7: id%8==tm%8 -> A-strip's 8 readers share
// an XCD (FETCH 163->33 MB measured R6). Blocks with tm >= active strips exit.
__global__ __launch_bounds__(256) void gemm_kernel(const unsigned short* __restrict__ A,
                                                   const unsigned short* __restrict__ B,
                                                   const float* __restrict__ b2,
                                                   const float* __restrict__ Wf,
                                                   const int* __restrict__ nm,
                                                   float* __restrict__ logitsC) {
    __shared__ unsigned short As[4096];  // 128 rows x 32 k (bf16) = 8 KB
    __shared__ unsigned short Bs[4096];
    const int tid = threadIdx.x;
    __shared__ int s_nm;
    if (tid == 0) s_nm = nm[0];
    __syncthreads();
    const int nmv = s_nm;
    const int mstrips = (nmv + 127) >> 7;
    const int bid = blockIdx.x;
    const int tm = (bid >> 6) * 8 + (bid & 7);   // 0..159, tm%8 == bid%8
    const int tn = (bid >> 3) & 7;
    if (tm >= mstrips) return;
    const int lane = tid & 63;
    const int wv = tid >> 6;
    const int wr = wv >> 1, wc = wv & 1;

    const int chunk = ((tid & 3) ^ ((tid >> 3) & 3)) * 16;
    const int rsub = tid >> 2;   // row 0..63 (+64 in round 1)
    const char* Ag = (const char*)(A + (size_t)(tm * 128 + rsub) * KP) + chunk;
    const char* Bg = (const char*)(B + (size_t)(tn * 128 + rsub) * KP) + chunk;
    char* AsW = (char*)As + wv * 1024;
    char* BsW = (char*)Bs + wv * 1024;

    f32x4 acc[4][4];
#pragma unroll
    for (int i = 0; i < 4; ++i)
#pragma unroll
        for (int j = 0; j < 4; ++j) acc[i][j] = (f32x4){0.f, 0.f, 0.f, 0.f};

    const int m = lane & 15;
    const int quad = lane >> 4;
    const int sw = quad ^ ((m >> 1) & 3);       // swizzled k-chunk slot
    const int aoff = (wr * 64 + m) * 64 + sw * 16;
    const int boff = (wc * 64 + m) * 64 + sw * 16;

    for (int kk = 0; kk < KP; kk += 32) {
        __syncthreads();
        const int kb = kk * 2;
        gld_lds16(Ag + kb,             AsW);
        gld_lds16(Ag + kb + 64 * 2048, AsW + 4096);
        gld_lds16(Bg + kb,             BsW);
        gld_lds16(Bg + kb + 64 * 2048, BsW + 4096);
        __syncthreads();
        bf16x8 af[4], bfv[4];
#pragma unroll
        for (int mt = 0; mt < 4; ++mt)
            af[mt] = *(const bf16x8*)((const char*)As + aoff + mt * 1024);
#pragma unroll
        for (int nt = 0; nt < 4; ++nt)
            bfv[nt] = *(const bf16x8*)((const char*)Bs + boff + nt * 1024);
#pragma unroll
        for (int mt = 0; mt < 4; ++mt)
#pragma unroll
            for (int nt = 0; nt < 4; ++nt)
                acc[mt][nt] = __builtin_amdgcn_mfma_f32_16x16x32_bf16(af[mt], bfv[nt], acc[mt][nt], 0, 0, 0);
    }

    // epilogue: C/D layout col = lane&15, row = quad*4 + reg
    const int col0 = tn * 128 + wc * 64 + m;
    const int row00 = tm * 128 + wr * 64 + quad * 4;
#pragma unroll
    for (int mt = 0; mt < 4; ++mt) {
        float ps0 = 0.f, ps1 = 0.f, ps2 = 0.f, ps3 = 0.f;
#pragma unroll
        for (int nt = 0; nt < 4; ++nt) {
            const int c = col0 + nt * 16;
            const float bb = (c < 1000) ? b2[c] : 0.0f;
            const float wf = (c < 1000) ? Wf[c] : 0.0f;
            ps0 += fmaxf(acc[mt][nt][0] + bb, 0.f) * wf;
            ps1 += fmaxf(acc[mt][nt][1] + bb, 0.f) * wf;
            ps2 += fmaxf(acc[mt][nt][2] + bb, 0.f) * wf;
            ps3 += fmaxf(acc[mt][nt][3] + bb, 0.f) * wf;
        }
#pragma unroll
        for (int msk = 1; msk < 16; msk <<= 1) {
            ps0 += __shfl_xor(ps0, msk);
            ps1 += __shfl_xor(ps1, msk);
            ps2 += __shfl_xor(ps2, msk);
            ps3 += __shfl_xor(ps3, msk);
        }
        if (m == 0) {
            const int row = row00 + mt * 16;
            if (row + 0 < nmv) atomicAdd(&logitsC[row + 0], ps0);
            if (row + 1 < nmv) atomicAdd(&logitsC[row + 1], ps1);
            if (row + 2 < nmv) atomicAdd(&logitsC[row + 2], ps2);
            if (row + 3 < nmv) atomicAdd(&logitsC[row + 3], ps3);
        }
    }
}

// segment softmax over compact (all-masked) logits; bc sorted -> binary search.
// out pre-zeroed by memset; only masked slots written via perm.
__global__ __launch_bounds__(256) void softmax_kernel(const float* __restrict__ logitsC,
        const int* __restrict__ perm, const int* __restrict__ bc,
        const int* __restrict__ nm, float* __restrict__ out) {
    const int g = blockIdx.x;
    const int t = threadIdx.x;
    __shared__ int s_lo, s_hi;
    __shared__ float red[4];
    __shared__ float sval;
    if (t == 0) {
        const int nmv = nm[0];
        int lo = 0, hi = nmv;
        while (lo < hi) { const int mid = (lo + hi) >> 1; if (bc[mid] < g) lo = mid + 1; else hi = mid; }
        s_lo = lo;
        int lo2 = lo, hi2 = nmv;
        while (lo2 < hi2) { const int mid = (lo2 + hi2) >> 1; if (bc[mid] < g + 1) lo2 = mid + 1; else hi2 = mid; }
        s_hi = lo2;
    }
    __syncthreads();
    const int lo = s_lo, hi = s_hi;
    float mx = -1e30f;
    for (int i = lo + t; i < hi; i += 256) mx = fmaxf(mx, logitsC[i]);
    for (int off = 32; off; off >>= 1) mx = fmaxf(mx, __shfl_down(mx, off));
    if ((t & 63) == 0) red[t >> 6] = mx;
    __syncthreads();
    if (t == 0) sval = fmaxf(fmaxf(red[0], red[1]), fmaxf(red[2], red[3]));
    __syncthreads();
    mx = sval;
    __syncthreads();
    float sm = 0.f;
    for (int i = lo + t; i < hi; i += 256) sm += expf(logitsC[i] - mx);
    for (int off = 32; off; off >>= 1) sm += __shfl_down(sm, off);
    if ((t & 63) == 0) red[t >> 6] = sm;
    __syncthreads();
    if (t == 0) sval = red[0] + red[1] + red[2] + red[3];
    __syncthreads();
    const float inv = 1.0f / fmaxf(sval, 1e-16f);
    for (int i = lo + t; i < hi; i += 256)
        out[perm[i]] = expf(logitsC[i] - mx) * inv;
}

extern "C" void kernel_launch(void* const* d_in, const int* in_sizes, int n_in,
                              void* d_out, int out_size, void* d_ws, size_t ws_size,
                              hipStream_t stream) {
    (void)in_sizes; (void)n_in; (void)ws_size;
    const float* x   = (const float*)d_in[0];
    const float* ew  = (const float*)d_in[1];
    const float* W1  = (const float*)d_in[2];
    const float* b1  = (const float*)d_in[3];
    const float* W2  = (const float*)d_in[4];
    const float* b2  = (const float*)d_in[5];
    const float* Wf  = (const float*)d_in[6];
    const int*   ei  = (const int*)d_in[8];
    const void*  mask  = d_in[9];
    const int*   batch = (const int*)d_in[10];
    float* out = (float*)d_out;

    char* p = (char*)d_ws;
    auto carve = [&](size_t bytes) { char* q = p; p += (bytes + 255) & ~(size_t)255; return q; };
    // zero-region (single hipMemsetAsync): deg, cnt, cursor, logitsC, flags
    char* zbase = p;
    float* deg     = (float*)carve(NN * 4);
    int*   cnt     = (int*)carve(NN * 4);
    int*   cursor  = (int*)carve(NN * 4);
    float* logitsC = (float*)carve(MPAD2 * 4);
    int*   flags   = (int*)carve(256);
    size_t zspan = (size_t)(p - zbase);
    int*   offs   = (int*)carve(NN * 4);
    float* dinv   = (float*)carve(NN * 4);
    int*   mtmp   = (int*)carve(NN * 4);
    int*   perm   = (int*)carve(NN * 4);
    int*   bc     = (int*)carve(NN * 4);
    int*   bcnt   = (int*)carve(NBLK * 4);
    int*   bmsk   = (int*)carve(NBLK * 4);
    int*   nmp    = (int*)carve(256);
    int*   ssrc   = (int*)carve(NE * 4);
    float* snorm  = (float*)carve(NE * 4);
    float* Ax     = (float*)carve(NN * 5 * 4);
    unsigned short* W2t = (unsigned short*)carve((size_t)KP * KP * 2);
    unsigned short* h1  = (unsigned short*)carve((size_t)NN * KP * 2);
    unsigned short* G   = (unsigned short*)carve((size_t)MPAD2 * KP * 2);

    hipMemsetAsync(zbase, 0, zspan, stream);
    hipMemsetAsync(out, 0, (size_t)out_size * 4, stream);
    hipLaunchKernelGGL(deg_cnt_kernel,  dim3(625),   dim3(256),  0, stream, ei, ew, deg, cnt, mask, flags);
    hipLaunchKernelGGL(partial_kernel,  dim3(NBLK),  dim3(256),  0, stream, cnt, deg, mask, flags, mtmp, dinv, bcnt, bmsk);
    hipLaunchKernelGGL(scanp_kernel,    dim3(1),     dim3(128),  0, stream, bcnt, bmsk, nmp);
    hipLaunchKernelGGL(apply_kernel,    dim3(NBLK),  dim3(256),  0, stream, cnt, mtmp, bcnt, bmsk, batch, offs, perm, bc);
    hipLaunchKernelGGL(scatter_kernel,  dim3(625),   dim3(256),  0, stream, ei, ew, dinv, offs, cursor, ssrc, snorm);
    hipLaunchKernelGGL(ax_kernel,       dim3(79),    dim3(256),  0, stream, x, ssrc, snorm, offs, cnt, Ax);
    hipLaunchKernelGGL(prep_kernel,     dim3(2274),  dim3(256),  0, stream, Ax, x, dinv, W1, b1, h1, W2, W2t);
    hipLaunchKernelGGL(agg1k_kernel,    dim3(MPAD2), dim3(256),  0, stream, h1, ssrc, snorm, offs, cnt, dinv, perm, nmp, G);
    hipLaunchKernelGGL(gemm_kernel,     dim3(MT2*8), dim3(256),  0, stream, G, W2t, b2, Wf, nmp, logitsC);
    hipLaunchKernelGGL(softmax_kernel,  dim3(NG),    dim3(256),  0, stream, logitsC, perm, bc, nmp, out);
}